// Round 10
// baseline (56.172 us; speedup 1.0000x reference)
//
#include <hip/hip_runtime.h>

// FastHST fused: 4-level 1-D scattering, B=32, T=524288, K=16, PAD=8.
// Output: real-contiguous f32 (confirmed r3; harness compares in bf16).
//
// r8 (48.4us): issue-bound; steady-state HBM = writes only (input L3-resident).
// r9 lesson: 320-thr blocks regress (3 blocks/CU fit, occ 51%) -> stay 256-thr.
// r10: launch_bounds(256,8) (8 blocks/CU cap) + Karatsuba level-0:
//   stage SUM = re+im as third f16-pair stream; phase B uses 4 convs
//   (phi*re, psi_r*re, psi_i*im, (psi_r+psi_i)*sum) -> 32 dot2/pos vs 40.
//   ur = A - B, ui = C - A - B.
//
// f16 packed-pair storage + v_dot2_f32_f16 (2 MAC/issue, f32 accum).

using f16x2 = __attribute__((ext_vector_type(2))) __fp16;

static __device__ __forceinline__ uint packh2(float a, float b) {
    f16x2 r = __builtin_amdgcn_cvt_pkrtz(a, b);
    return __builtin_bit_cast(uint, r);
}
static __device__ __forceinline__ float dot2(f16x2 f, uint w, float c) {
#if __has_builtin(__builtin_amdgcn_fdot2)
    return __builtin_amdgcn_fdot2(f, __builtin_bit_cast(f16x2, w), c, false);
#else
    f16x2 h = __builtin_bit_cast(f16x2, w);
    return fmaf((float)f.x, (float)h.x, fmaf((float)f.y, (float)h.y, c));
#endif
}

constexpr int K    = 16;
constexpr int S1   = 1024;
constexpr int H1   = 56;              // x1 halo each side
constexpr int NT1  = S1 + 2 * H1;     // 1136 x1 values/block
constexpr int NG1  = NT1 / 4;         // 284 groups of 4
constexpr int NPIN = 1144;            // staged complex pairs
constexpr int NLD  = NPIN / 2;        // 572 float4 loads per stream
constexpr int NG2  = 140;             // ceil(560/4); NT2 = 560 (halo 24)
constexpr int NG3  = 68;              // NT3 = 272 (halo 8)
constexpr int NTH  = 256;             // 4 waves

__global__ __launch_bounds__(NTH, 8) void hst_fused_kernel(
    const float* __restrict__ xr, const float* __restrict__ xi,
    const float* __restrict__ psi_r, const float* __restrict__ psi_i,
    const float* __restrict__ phi,
    float* __restrict__ out,
    long o0, long o1, long o2, long o3,
    int L0, int h0, int h1, int h2, int h3)
{
    __shared__ __align__(16) uint REP[NPIN];   // re f16 pairs, 4.6KB
    __shared__ __align__(16) uint IMP[NPIN];   // im pairs, 4.6KB
    __shared__ __align__(16) uint SMP[NPIN];   // (re+im) pairs, 4.6KB
    __shared__ __align__(16) uint X1P[572];    // x1 pairs, 2.3KB
    __shared__ __align__(16) uint X2P[284];    // x2 pairs, 1.1KB
    __shared__ __align__(16) uint X3P[136];    // x3 pairs, 0.5KB

    const int tid = threadIdx.x;
    const int gx  = blockIdx.x;
    const int b   = blockIdx.y;
    const int s   = gx * S1;                  // first owned x1 index
    const bool edge = (gx == 0) || (gx == (int)gridDim.x - 1);
    const int X0  = 2 * (s - H1) - 8;         // first staged input idx (mult of 8)

    const float* rowr = xr + (size_t)b * (size_t)L0;
    const float* rowi = xi + (size_t)b * (size_t)L0;

    f16x2 FH[8], FR[8], FI[8], FS[8];
    #pragma unroll
    for (int j = 0; j < 8; ++j) {
        FH[j] = __builtin_amdgcn_cvt_pkrtz(phi[2*j],   phi[2*j+1]);
        FR[j] = __builtin_amdgcn_cvt_pkrtz(psi_r[2*j], psi_r[2*j+1]);
        FI[j] = __builtin_amdgcn_cvt_pkrtz(psi_i[2*j], psi_i[2*j+1]);
        FS[j] = __builtin_amdgcn_cvt_pkrtz(psi_r[2*j] + psi_i[2*j],
                                           psi_r[2*j+1] + psi_i[2*j+1]);
    }

    // ---- Phase A: stage input as f16 pairs (re, im, re+im) ----
    if (!edge) {
        const float4* pr4 = reinterpret_cast<const float4*>(rowr + X0);
        const float4* pi4 = reinterpret_cast<const float4*>(rowi + X0);
        #pragma unroll
        for (int n = 0; n < 3; ++n) {
            const int i = tid + n * NTH;
            if (i < NLD) {
                float4 a = pr4[i];
                float4 c = pi4[i];
                uint2 wa; wa.x = packh2(a.x, a.y); wa.y = packh2(a.z, a.w);
                uint2 wc; wc.x = packh2(c.x, c.y); wc.y = packh2(c.z, c.w);
                uint2 wsm; wsm.x = packh2(a.x + c.x, a.y + c.y);
                wsm.y = packh2(a.z + c.z, a.w + c.w);
                *reinterpret_cast<uint2*>(&REP[2*i]) = wa;
                *reinterpret_cast<uint2*>(&IMP[2*i]) = wc;
                *reinterpret_cast<uint2*>(&SMP[2*i]) = wsm;
            }
        }
    } else {
        for (int i = tid; i < NPIN; i += NTH) {
            int g0 = X0 + 2 * i;
            float r0 = (g0   >= 0 && g0   < L0) ? rowr[g0]   : 0.0f;
            float r1 = (g0+1 >= 0 && g0+1 < L0) ? rowr[g0+1] : 0.0f;
            float i0 = (g0   >= 0 && g0   < L0) ? rowi[g0]   : 0.0f;
            float i1 = (g0+1 >= 0 && g0+1 < L0) ? rowi[g0+1] : 0.0f;
            REP[i] = packh2(r0, r1);
            IMP[i] = packh2(i0, i1);
            SMP[i] = packh2(r0 + i0, r1 + i1);
        }
    }
    __syncthreads();

    // ---- Phase B: level 0 -> c0 (re) + X1P = |psi*x| decimated ----
    // pos lm=4g+r uses pair-words (4g+r)..(4g+r+7); group loads 4g..4g+11.
    #pragma unroll
    for (int n = 0; n < 2; ++n) {
        const int g = tid + n * NTH;
        if (g < NG1) {
            const uint4* wp = reinterpret_cast<const uint4*>(&REP[4*g]);
            uint4 a0 = wp[0], a1 = wp[1], a2 = wp[2];
            const uint wr[12] = {a0.x,a0.y,a0.z,a0.w, a1.x,a1.y,a1.z,a1.w, a2.x,a2.y,a2.z,a2.w};
            const uint4* ip = reinterpret_cast<const uint4*>(&IMP[4*g]);
            uint4 c0v = ip[0], c1v = ip[1], c2v = ip[2];
            const uint wi[12] = {c0v.x,c0v.y,c0v.z,c0v.w, c1v.x,c1v.y,c1v.z,c1v.w, c2v.x,c2v.y,c2v.z,c2v.w};
            const uint4* spp = reinterpret_cast<const uint4*>(&SMP[4*g]);
            uint4 s0v = spp[0], s1v = spp[1], s2v = spp[2];
            const uint wsm[12] = {s0v.x,s0v.y,s0v.z,s0v.w, s1v.x,s1v.y,s1v.z,s1v.w, s2v.x,s2v.y,s2v.z,s2v.w};

            float phv[4], mag[4];
            #pragma unroll
            for (int r = 0; r < 4; ++r) {
                float sh = 0.f, A = 0.f, Bv = 0.f, C = 0.f;
                #pragma unroll
                for (int j = 0; j < 8; ++j) {
                    sh = dot2(FH[j], wr[r+j], sh);
                    A  = dot2(FR[j], wr[r+j], A);
                    Bv = dot2(FI[j], wi[r+j], Bv);
                    C  = dot2(FS[j], wsm[r+j], C);
                }
                float ur = A - Bv;
                float ui = C - (A + Bv);
                float m2 = sqrtf(fmaf(ur, ur, ui * ui));
                if (edge) {
                    int m = s - H1 + 4*g + r;
                    m2 = (m >= 0 && m < h0) ? m2 : 0.0f;
                }
                mag[r] = m2;
                phv[r] = sh;
            }
            uint2 xp; xp.x = packh2(mag[0], mag[1]); xp.y = packh2(mag[2], mag[3]);
            *reinterpret_cast<uint2*>(&X1P[2*g]) = xp;

            if (g >= H1/4 && g < H1/4 + S1/4) {   // owned lm in [56,1080)
                long m0 = (long)s - H1 + 4*g;
                float4 st; st.x = phv[0]; st.y = phv[1]; st.z = phv[2]; st.w = phv[3];
                *reinterpret_cast<float4*>(out + o0 + (long)b * h0 + m0) = st;
            }
        }
    }
    __syncthreads();

    // ---- Phase C: level 1 -> c1 + X2P ----
    if (tid < NG2) {
        const int g = tid;
        const uint4* wp = reinterpret_cast<const uint4*>(&X1P[4*g]);
        uint4 a0 = wp[0], a1 = wp[1], a2 = wp[2];
        const uint w[12] = {a0.x,a0.y,a0.z,a0.w, a1.x,a1.y,a1.z,a1.w, a2.x,a2.y,a2.z,a2.w};

        float phv[4], mag[4];
        #pragma unroll
        for (int r = 0; r < 4; ++r) {
            float sh = 0.f, ur = 0.f, ui = 0.f;
            #pragma unroll
            for (int j = 0; j < 8; ++j) {
                sh = dot2(FH[j], w[r+j], sh);
                ur = dot2(FR[j], w[r+j], ur);
                ui = dot2(FI[j], w[r+j], ui);
            }
            float m2 = sqrtf(fmaf(ur, ur, ui * ui));
            const int q = s/2 - 24 + 4*g + r;
            if (edge) m2 = (q >= 0 && q < h1) ? m2 : 0.0f;
            mag[r] = m2;
            phv[r] = sh;
        }
        uint2 xp; xp.x = packh2(mag[0], mag[1]); xp.y = packh2(mag[2], mag[3]);
        *reinterpret_cast<uint2*>(&X2P[2*g]) = xp;

        if (g >= 6 && g < 6 + S1/8) {            // owned lq in [24,536)
            long q0 = (long)s/2 - 24 + 4*g;
            float4 st; st.x = phv[0]; st.y = phv[1]; st.z = phv[2]; st.w = phv[3];
            *reinterpret_cast<float4*>(out + o1 + (long)b * h1 + q0) = st;
        }
    }
    __syncthreads();

    // ---- Phase D: level 2 -> c2 + X3P ----
    if (tid < NG3) {
        const int g = tid;
        const uint4* wp = reinterpret_cast<const uint4*>(&X2P[4*g]);
        uint4 a0 = wp[0], a1 = wp[1], a2 = wp[2];
        const uint w[12] = {a0.x,a0.y,a0.z,a0.w, a1.x,a1.y,a1.z,a1.w, a2.x,a2.y,a2.z,a2.w};

        float phv[4], mag[4];
        #pragma unroll
        for (int r = 0; r < 4; ++r) {
            float sh = 0.f, ur = 0.f, ui = 0.f;
            #pragma unroll
            for (int j = 0; j < 8; ++j) {
                sh = dot2(FH[j], w[r+j], sh);
                ur = dot2(FR[j], w[r+j], ur);
                ui = dot2(FI[j], w[r+j], ui);
            }
            float m2 = sqrtf(fmaf(ur, ur, ui * ui));
            const int p = s/4 - 8 + 4*g + r;
            if (edge) m2 = (p >= 0 && p < h2) ? m2 : 0.0f;
            mag[r] = m2;
            phv[r] = sh;
        }
        uint2 xp; xp.x = packh2(mag[0], mag[1]); xp.y = packh2(mag[2], mag[3]);
        *reinterpret_cast<uint2*>(&X3P[2*g]) = xp;

        if (g >= 2 && g < 2 + S1/16) {           // owned lp in [8,264)
            long p0 = (long)s/4 - 8 + 4*g;
            float4 st; st.x = phv[0]; st.y = phv[1]; st.z = phv[2]; st.w = phv[3];
            *reinterpret_cast<float4*>(out + o2 + (long)b * h2 + p0) = st;
        }
    }
    __syncthreads();

    // ---- Phase E: level 3 -> c3 (phi only; x4 unused by reference) ----
    if (tid < S1/8) {
        float sh = 0.f;
        #pragma unroll
        for (int j = 0; j < 8; ++j)
            sh = dot2(FH[j], X3P[tid + j], sh);
        out[o3 + (long)b * h3 + (s/8 + tid)] = sh;
    }
}

extern "C" void kernel_launch(void* const* d_in, const int* in_sizes, int n_in,
                              void* d_out, int out_size, void* d_ws, size_t ws_size,
                              hipStream_t stream) {
    const float* xr    = (const float*)d_in[0];
    const float* xi    = (const float*)d_in[1];
    const float* psi_r = (const float*)d_in[2];
    const float* psi_i = (const float*)d_in[3];
    const float* phi   = (const float*)d_in[4];
    float* out = (float*)d_out;

    const int B  = 32;
    const int T  = in_sizes[0] / B;      // 524288
    const int L0 = T;
    const int h0 = L0 / 2;               // 262144
    const int h1 = h0 / 2;               // 131072
    const int h2 = h1 / 2;               // 65536
    const int h3 = h2 / 2;               // 32768

    const long o0 = 0;
    const long o1 = o0 + (long)B * h0;
    const long o2 = o1 + (long)B * h1;
    const long o3 = o2 + (long)B * h2;

    dim3 blk(NTH, 1, 1);
    dim3 grd(h0 / S1, B, 1);             // (256, 32)
    hipLaunchKernelGGL(hst_fused_kernel, grd, blk, 0, stream,
                       xr, xi, psi_r, psi_i, phi,
                       out, o0, o1, o2, o3,
                       L0, h0, h1, h2, h3);
}

// Round 11
// 52.581 us; speedup vs baseline: 1.0683x; 1.0683x over previous
//
#include <hip/hip_runtime.h>

// FastHST fused: 4-level 1-D scattering, B=32, T=524288, K=16, PAD=8.
// Output: real-contiguous f32 (confirmed r3; harness compares in bf16).
//
// r8 (48.4us): issue-bound; steady-state HBM = writes only (input L3-resident).
// r9 lesson: 320-thr blocks regress (bad packing, occ 51%) -> stay 256-thr.
// r10 lesson: Karatsuba 3rd stream spilled (+36MB scratch writes) -> reverted.
// r11: exact r8 kernel, single change: launch_bounds(256,6) -> (256,8).
//
// f16 packed-pair storage + v_dot2_f32_f16 (2 MAC/issue, f32 accum).

using f16x2 = __attribute__((ext_vector_type(2))) __fp16;

static __device__ __forceinline__ uint packh2(float a, float b) {
    f16x2 r = __builtin_amdgcn_cvt_pkrtz(a, b);
    return __builtin_bit_cast(uint, r);
}
static __device__ __forceinline__ float dot2(f16x2 f, uint w, float c) {
#if __has_builtin(__builtin_amdgcn_fdot2)
    return __builtin_amdgcn_fdot2(f, __builtin_bit_cast(f16x2, w), c, false);
#else
    f16x2 h = __builtin_bit_cast(f16x2, w);
    return fmaf((float)f.x, (float)h.x, fmaf((float)f.y, (float)h.y, c));
#endif
}

constexpr int K    = 16;
constexpr int S1   = 1024;
constexpr int H1   = 56;              // x1 halo each side
constexpr int NT1  = S1 + 2 * H1;     // 1136 x1 values/block
constexpr int NG1  = NT1 / 4;         // 284 groups of 4
constexpr int NPIN = 1144;            // staged complex pairs
constexpr int NLD  = NPIN / 2;        // 572 float4 loads per stream
constexpr int NG2  = 140;             // ceil(560/4); NT2 = 560 (halo 24)
constexpr int NG3  = 68;              // NT3 = 272 (halo 8)
constexpr int NTH  = 256;             // 4 waves

__global__ __launch_bounds__(NTH, 8) void hst_fused_kernel(
    const float* __restrict__ xr, const float* __restrict__ xi,
    const float* __restrict__ psi_r, const float* __restrict__ psi_i,
    const float* __restrict__ phi,
    float* __restrict__ out,
    long o0, long o1, long o2, long o3,
    int L0, int h0, int h1, int h2, int h3)
{
    __shared__ __align__(16) uint REP[NPIN];   // re f16 pairs, 4.6KB
    __shared__ __align__(16) uint IMP[NPIN];   // im pairs, 4.6KB
    __shared__ __align__(16) uint X1P[572];    // x1 pairs, 2.3KB
    __shared__ __align__(16) uint X2P[284];    // x2 pairs, 1.1KB
    __shared__ __align__(16) uint X3P[136];    // x3 pairs, 0.5KB

    const int tid = threadIdx.x;
    const int gx  = blockIdx.x;
    const int b   = blockIdx.y;
    const int s   = gx * S1;                  // first owned x1 index
    const bool edge = (gx == 0) || (gx == (int)gridDim.x - 1);
    const int X0  = 2 * (s - H1) - 8;         // first staged input idx (mult of 8)

    const float* rowr = xr + (size_t)b * (size_t)L0;
    const float* rowi = xi + (size_t)b * (size_t)L0;

    f16x2 FH[8], FR[8], FI[8];
    #pragma unroll
    for (int j = 0; j < 8; ++j) {
        FH[j] = __builtin_amdgcn_cvt_pkrtz(phi[2*j],   phi[2*j+1]);
        FR[j] = __builtin_amdgcn_cvt_pkrtz(psi_r[2*j], psi_r[2*j+1]);
        FI[j] = __builtin_amdgcn_cvt_pkrtz(psi_i[2*j], psi_i[2*j+1]);
    }

    // ---- Phase A: stage input as f16 pairs ----
    if (!edge) {
        const float4* pr4 = reinterpret_cast<const float4*>(rowr + X0);
        const float4* pi4 = reinterpret_cast<const float4*>(rowi + X0);
        #pragma unroll
        for (int n = 0; n < 3; ++n) {
            const int i = tid + n * NTH;
            if (i < NLD) {
                float4 a = pr4[i];
                float4 c = pi4[i];
                uint2 wa; wa.x = packh2(a.x, a.y); wa.y = packh2(a.z, a.w);
                uint2 wc; wc.x = packh2(c.x, c.y); wc.y = packh2(c.z, c.w);
                *reinterpret_cast<uint2*>(&REP[2*i]) = wa;
                *reinterpret_cast<uint2*>(&IMP[2*i]) = wc;
            }
        }
    } else {
        for (int i = tid; i < NPIN; i += NTH) {
            int g0 = X0 + 2 * i;
            float r0 = (g0   >= 0 && g0   < L0) ? rowr[g0]   : 0.0f;
            float r1 = (g0+1 >= 0 && g0+1 < L0) ? rowr[g0+1] : 0.0f;
            float i0 = (g0   >= 0 && g0   < L0) ? rowi[g0]   : 0.0f;
            float i1 = (g0+1 >= 0 && g0+1 < L0) ? rowi[g0+1] : 0.0f;
            REP[i] = packh2(r0, r1);
            IMP[i] = packh2(i0, i1);
        }
    }
    __syncthreads();

    // ---- Phase B: level 0 -> c0 (re) + X1P = |psi*x| decimated ----
    // position lm=4g+r uses pair-words (4g+r)..(4g+r+7); group loads 4g..4g+11.
    #pragma unroll
    for (int n = 0; n < 2; ++n) {
        const int g = tid + n * NTH;
        if (g < NG1) {
            const uint4* wp = reinterpret_cast<const uint4*>(&REP[4*g]);
            uint4 a0 = wp[0], a1 = wp[1], a2 = wp[2];
            const uint4* ip = reinterpret_cast<const uint4*>(&IMP[4*g]);
            uint4 c0v = ip[0], c1v = ip[1], c2v = ip[2];
            const uint wr[12] = {a0.x,a0.y,a0.z,a0.w, a1.x,a1.y,a1.z,a1.w, a2.x,a2.y,a2.z,a2.w};
            const uint wi[12] = {c0v.x,c0v.y,c0v.z,c0v.w, c1v.x,c1v.y,c1v.z,c1v.w, c2v.x,c2v.y,c2v.z,c2v.w};

            float phv[4], mag[4];
            #pragma unroll
            for (int r = 0; r < 4; ++r) {
                float sh = 0.f, rr = 0.f, ri = 0.f, ir = 0.f, ii = 0.f;
                #pragma unroll
                for (int j = 0; j < 8; ++j) {
                    sh = dot2(FH[j], wr[r+j], sh);
                    rr = dot2(FR[j], wr[r+j], rr);
                    ri = dot2(FI[j], wr[r+j], ri);
                    ir = dot2(FR[j], wi[r+j], ir);
                    ii = dot2(FI[j], wi[r+j], ii);
                }
                float ur = rr - ii, ui = ri + ir;
                float m2 = sqrtf(fmaf(ur, ur, ui * ui));
                if (edge) {
                    int m = s - H1 + 4*g + r;
                    m2 = (m >= 0 && m < h0) ? m2 : 0.0f;
                }
                mag[r] = m2;
                phv[r] = sh;
            }
            uint2 xp; xp.x = packh2(mag[0], mag[1]); xp.y = packh2(mag[2], mag[3]);
            *reinterpret_cast<uint2*>(&X1P[2*g]) = xp;

            if (g >= H1/4 && g < H1/4 + S1/4) {   // owned lm in [56,1080)
                long m0 = (long)s - H1 + 4*g;
                float4 st; st.x = phv[0]; st.y = phv[1]; st.z = phv[2]; st.w = phv[3];
                *reinterpret_cast<float4*>(out + o0 + (long)b * h0 + m0) = st;
            }
        }
    }
    __syncthreads();

    // ---- Phase C: level 1 -> c1 + X2P ----
    if (tid < NG2) {
        const int g = tid;
        const uint4* wp = reinterpret_cast<const uint4*>(&X1P[4*g]);
        uint4 a0 = wp[0], a1 = wp[1], a2 = wp[2];
        const uint w[12] = {a0.x,a0.y,a0.z,a0.w, a1.x,a1.y,a1.z,a1.w, a2.x,a2.y,a2.z,a2.w};

        float phv[4], mag[4];
        #pragma unroll
        for (int r = 0; r < 4; ++r) {
            float sh = 0.f, ur = 0.f, ui = 0.f;
            #pragma unroll
            for (int j = 0; j < 8; ++j) {
                sh = dot2(FH[j], w[r+j], sh);
                ur = dot2(FR[j], w[r+j], ur);
                ui = dot2(FI[j], w[r+j], ui);
            }
            float m2 = sqrtf(fmaf(ur, ur, ui * ui));
            const int q = s/2 - 24 + 4*g + r;
            if (edge) m2 = (q >= 0 && q < h1) ? m2 : 0.0f;
            mag[r] = m2;
            phv[r] = sh;
        }
        uint2 xp; xp.x = packh2(mag[0], mag[1]); xp.y = packh2(mag[2], mag[3]);
        *reinterpret_cast<uint2*>(&X2P[2*g]) = xp;

        if (g >= 6 && g < 6 + S1/8) {            // owned lq in [24,536)
            long q0 = (long)s/2 - 24 + 4*g;
            float4 st; st.x = phv[0]; st.y = phv[1]; st.z = phv[2]; st.w = phv[3];
            *reinterpret_cast<float4*>(out + o1 + (long)b * h1 + q0) = st;
        }
    }
    __syncthreads();

    // ---- Phase D: level 2 -> c2 + X3P ----
    if (tid < NG3) {
        const int g = tid;
        const uint4* wp = reinterpret_cast<const uint4*>(&X2P[4*g]);
        uint4 a0 = wp[0], a1 = wp[1], a2 = wp[2];
        const uint w[12] = {a0.x,a0.y,a0.z,a0.w, a1.x,a1.y,a1.z,a1.w, a2.x,a2.y,a2.z,a2.w};

        float phv[4], mag[4];
        #pragma unroll
        for (int r = 0; r < 4; ++r) {
            float sh = 0.f, ur = 0.f, ui = 0.f;
            #pragma unroll
            for (int j = 0; j < 8; ++j) {
                sh = dot2(FH[j], w[r+j], sh);
                ur = dot2(FR[j], w[r+j], ur);
                ui = dot2(FI[j], w[r+j], ui);
            }
            float m2 = sqrtf(fmaf(ur, ur, ui * ui));
            const int p = s/4 - 8 + 4*g + r;
            if (edge) m2 = (p >= 0 && p < h2) ? m2 : 0.0f;
            mag[r] = m2;
            phv[r] = sh;
        }
        uint2 xp; xp.x = packh2(mag[0], mag[1]); xp.y = packh2(mag[2], mag[3]);
        *reinterpret_cast<uint2*>(&X3P[2*g]) = xp;

        if (g >= 2 && g < 2 + S1/16) {           // owned lp in [8,264)
            long p0 = (long)s/4 - 8 + 4*g;
            float4 st; st.x = phv[0]; st.y = phv[1]; st.z = phv[2]; st.w = phv[3];
            *reinterpret_cast<float4*>(out + o2 + (long)b * h2 + p0) = st;
        }
    }
    __syncthreads();

    // ---- Phase E: level 3 -> c3 (phi only; x4 unused by reference) ----
    if (tid < S1/8) {
        float sh = 0.f;
        #pragma unroll
        for (int j = 0; j < 8; ++j)
            sh = dot2(FH[j], X3P[tid + j], sh);
        out[o3 + (long)b * h3 + (s/8 + tid)] = sh;
    }
}

extern "C" void kernel_launch(void* const* d_in, const int* in_sizes, int n_in,
                              void* d_out, int out_size, void* d_ws, size_t ws_size,
                              hipStream_t stream) {
    const float* xr    = (const float*)d_in[0];
    const float* xi    = (const float*)d_in[1];
    const float* psi_r = (const float*)d_in[2];
    const float* psi_i = (const float*)d_in[3];
    const float* phi   = (const float*)d_in[4];
    float* out = (float*)d_out;

    const int B  = 32;
    const int T  = in_sizes[0] / B;      // 524288
    const int L0 = T;
    const int h0 = L0 / 2;               // 262144
    const int h1 = h0 / 2;               // 131072
    const int h2 = h1 / 2;               // 65536
    const int h3 = h2 / 2;               // 32768

    const long o0 = 0;
    const long o1 = o0 + (long)B * h0;
    const long o2 = o1 + (long)B * h1;
    const long o3 = o2 + (long)B * h2;

    dim3 blk(NTH, 1, 1);
    dim3 grd(h0 / S1, B, 1);             // (256, 32)
    hipLaunchKernelGGL(hst_fused_kernel, grd, blk, 0, stream,
                       xr, xi, psi_r, psi_i, phi,
                       out, o0, o1, o2, o3,
                       L0, h0, h1, h2, h3);
}

// Round 12
// 49.320 us; speedup vs baseline: 1.1389x; 1.0661x over previous
//
#include <hip/hip_runtime.h>

// FastHST fused: 4-level 1-D scattering, B=32, T=524288, K=16, PAD=8.
// Output: real-contiguous f32 (confirmed r3; harness compares in bf16).
//
// r8 (48.4us, launch_bounds(256,6)) reference. r9/r11: occupancy levers
// regressed -> occupancy not binding. r10: Karatsuba spilled -> reverted.
// r12: fix intra-block wave imbalance. Old mapping made wave 0 issue 2x
// (phase B second pass hit threads 0-27 only; C used 140/256 threads, D
// 68/256). New tiling: B = 256 exact groups + 112-position halo pass spread
// 28/wave (scalar __fp16 LDS writes); C = 2 pos/thread x256 + 48 singles
// 12/wave; D = 2 pos/thread x136. Per-wave critical dot2: 520 -> ~328.
//
// f16 packed-pair storage + v_dot2_f32_f16 (2 MAC/issue, f32 accum).

using f16x2 = __attribute__((ext_vector_type(2))) __fp16;

static __device__ __forceinline__ uint packh2(float a, float b) {
    f16x2 r = __builtin_amdgcn_cvt_pkrtz(a, b);
    return __builtin_bit_cast(uint, r);
}
static __device__ __forceinline__ float dot2(f16x2 f, uint w, float c) {
#if __has_builtin(__builtin_amdgcn_fdot2)
    return __builtin_amdgcn_fdot2(f, __builtin_bit_cast(f16x2, w), c, false);
#else
    f16x2 h = __builtin_bit_cast(f16x2, w);
    return fmaf((float)f.x, (float)h.x, fmaf((float)f.y, (float)h.y, c));
#endif
}

constexpr int S1   = 1024;
constexpr int H1   = 56;              // x1 halo each side
constexpr int NT1  = S1 + 2 * H1;     // 1136 x1 values/block
constexpr int NPIN = 1144;            // staged complex pairs
constexpr int NLD  = NPIN / 2;        // 572 float4 loads per stream
constexpr int NTH  = 256;             // 4 waves

__global__ __launch_bounds__(NTH, 6) void hst_fused_kernel(
    const float* __restrict__ xr, const float* __restrict__ xi,
    const float* __restrict__ psi_r, const float* __restrict__ psi_i,
    const float* __restrict__ phi,
    float* __restrict__ out,
    long o0, long o1, long o2, long o3,
    int L0, int h0, int h1, int h2, int h3)
{
    __shared__ __align__(16) uint REP[NPIN];   // re f16 pairs, 4.6KB
    __shared__ __align__(16) uint IMP[NPIN];   // im pairs, 4.6KB
    __shared__ __align__(16) uint X1P[572];    // x1 pairs (1136+ halfs), 2.3KB
    __shared__ __align__(16) uint X2P[284];    // x2 pairs (560 halfs), 1.1KB
    __shared__ __align__(16) uint X3P[136];    // x3 pairs (272 halfs), 0.5KB

    const int tid  = threadIdx.x;
    const int wv   = tid >> 6;                // wave id 0..3
    const int lane = tid & 63;
    const int gx   = blockIdx.x;
    const int b    = blockIdx.y;
    const int s    = gx * S1;                 // first owned x1 index
    const bool edge = (gx == 0) || (gx == (int)gridDim.x - 1);
    const int X0   = 2 * (s - H1) - 8;        // first staged input idx

    const float* rowr = xr + (size_t)b * (size_t)L0;
    const float* rowi = xi + (size_t)b * (size_t)L0;

    f16x2 FH[8], FR[8], FI[8];
    #pragma unroll
    for (int j = 0; j < 8; ++j) {
        FH[j] = __builtin_amdgcn_cvt_pkrtz(phi[2*j],   phi[2*j+1]);
        FR[j] = __builtin_amdgcn_cvt_pkrtz(psi_r[2*j], psi_r[2*j+1]);
        FI[j] = __builtin_amdgcn_cvt_pkrtz(psi_i[2*j], psi_i[2*j+1]);
    }

    // ---- Phase A: stage input as f16 pairs (tail spread 15/wave) ----
    if (!edge) {
        const float4* pr4 = reinterpret_cast<const float4*>(rowr + X0);
        const float4* pi4 = reinterpret_cast<const float4*>(rowi + X0);
        #pragma unroll
        for (int n = 0; n < 2; ++n) {
            const int i = tid + n * NTH;
            float4 a = pr4[i];
            float4 c = pi4[i];
            uint2 wa; wa.x = packh2(a.x, a.y); wa.y = packh2(a.z, a.w);
            uint2 wc; wc.x = packh2(c.x, c.y); wc.y = packh2(c.z, c.w);
            *reinterpret_cast<uint2*>(&REP[2*i]) = wa;
            *reinterpret_cast<uint2*>(&IMP[2*i]) = wc;
        }
        if (lane < 15) {
            const int i = 512 + 4 * lane + wv;     // 512..571
            if (i < NLD) {
                float4 a = pr4[i];
                float4 c = pi4[i];
                uint2 wa; wa.x = packh2(a.x, a.y); wa.y = packh2(a.z, a.w);
                uint2 wc; wc.x = packh2(c.x, c.y); wc.y = packh2(c.z, c.w);
                *reinterpret_cast<uint2*>(&REP[2*i]) = wa;
                *reinterpret_cast<uint2*>(&IMP[2*i]) = wc;
            }
        }
    } else {
        for (int i = tid; i < NPIN; i += NTH) {
            int g0 = X0 + 2 * i;
            float r0 = (g0   >= 0 && g0   < L0) ? rowr[g0]   : 0.0f;
            float r1 = (g0+1 >= 0 && g0+1 < L0) ? rowr[g0+1] : 0.0f;
            float i0 = (g0   >= 0 && g0   < L0) ? rowi[g0]   : 0.0f;
            float i1 = (g0+1 >= 0 && g0+1 < L0) ? rowi[g0+1] : 0.0f;
            REP[i] = packh2(r0, r1);
            IMP[i] = packh2(i0, i1);
        }
    }
    __syncthreads();

    // ---- Phase B main: positions 0..1023, exactly 1 group of 4 per thread ----
    {
        const int g = tid;                    // pair-word base 4g
        const uint4* wp = reinterpret_cast<const uint4*>(&REP[4*g]);
        uint4 a0 = wp[0], a1 = wp[1], a2 = wp[2];
        const uint4* ip = reinterpret_cast<const uint4*>(&IMP[4*g]);
        uint4 c0v = ip[0], c1v = ip[1], c2v = ip[2];
        const uint wr[12] = {a0.x,a0.y,a0.z,a0.w, a1.x,a1.y,a1.z,a1.w, a2.x,a2.y,a2.z,a2.w};
        const uint wi[12] = {c0v.x,c0v.y,c0v.z,c0v.w, c1v.x,c1v.y,c1v.z,c1v.w, c2v.x,c2v.y,c2v.z,c2v.w};

        float phv[4], mag[4];
        #pragma unroll
        for (int r = 0; r < 4; ++r) {
            float sh = 0.f, rr = 0.f, ri = 0.f, ir = 0.f, ii = 0.f;
            #pragma unroll
            for (int j = 0; j < 8; ++j) {
                sh = dot2(FH[j], wr[r+j], sh);
                rr = dot2(FR[j], wr[r+j], rr);
                ri = dot2(FI[j], wr[r+j], ri);
                ir = dot2(FR[j], wi[r+j], ir);
                ii = dot2(FI[j], wi[r+j], ii);
            }
            float ur = rr - ii, ui = ri + ir;
            float m2 = sqrtf(fmaf(ur, ur, ui * ui));
            if (edge) {
                int m = s - H1 + 4*g + r;
                m2 = (m >= 0 && m < h0) ? m2 : 0.0f;
            }
            mag[r] = m2;
            phv[r] = sh;
        }
        uint2 xp; xp.x = packh2(mag[0], mag[1]); xp.y = packh2(mag[2], mag[3]);
        *reinterpret_cast<uint2*>(&X1P[2*g]) = xp;

        if (g >= 14) {                        // positions 56..1023 owned
            long m0 = (long)s - H1 + 4*g;
            float4 st; st.x = phv[0]; st.y = phv[1]; st.z = phv[2]; st.w = phv[3];
            *reinterpret_cast<float4*>(out + o0 + (long)b * h0 + m0) = st;
        }
    }

    // ---- Phase B halo: positions 1024..1135, 28 singles per wave ----
    if (lane < 28) {
        const int h  = 4 * lane + wv;         // 0..111
        const int lm = 1024 + h;
        uint wr8[8], wi8[8];
        #pragma unroll
        for (int j = 0; j < 8; ++j) { wr8[j] = REP[lm + j]; wi8[j] = IMP[lm + j]; }
        float sh = 0.f, rr = 0.f, ri = 0.f, ir = 0.f, ii = 0.f;
        #pragma unroll
        for (int j = 0; j < 8; ++j) {
            sh = dot2(FH[j], wr8[j], sh);
            rr = dot2(FR[j], wr8[j], rr);
            ri = dot2(FI[j], wr8[j], ri);
            ir = dot2(FR[j], wi8[j], ir);
            ii = dot2(FI[j], wi8[j], ii);
        }
        float ur = rr - ii, ui = ri + ir;
        float m2 = sqrtf(fmaf(ur, ur, ui * ui));
        if (edge) {
            int m = s - H1 + lm;
            m2 = (m >= 0 && m < h0) ? m2 : 0.0f;
        }
        reinterpret_cast<__fp16*>(X1P)[lm] = (__fp16)m2;
        if (h < 56)                            // positions 1024..1079 owned
            out[o0 + (long)b * h0 + (s + 968 + h)] = sh;
    }
    __syncthreads();

    // ---- Phase C main: positions 0..511 (2/thread) ----
    {
        const int t = tid;
        uint2 u0 = *reinterpret_cast<const uint2*>(&X1P[2*t]);
        uint2 u1 = *reinterpret_cast<const uint2*>(&X1P[2*t+2]);
        uint2 u2 = *reinterpret_cast<const uint2*>(&X1P[2*t+4]);
        uint2 u3 = *reinterpret_cast<const uint2*>(&X1P[2*t+6]);
        uint  w8 = X1P[2*t+8];
        const uint w[9] = {u0.x,u0.y,u1.x,u1.y,u2.x,u2.y,u3.x,u3.y,w8};

        float phv[2], mag[2];
        #pragma unroll
        for (int r = 0; r < 2; ++r) {
            float sh = 0.f, ur = 0.f, ui = 0.f;
            #pragma unroll
            for (int j = 0; j < 8; ++j) {
                sh = dot2(FH[j], w[r+j], sh);
                ur = dot2(FR[j], w[r+j], ur);
                ui = dot2(FI[j], w[r+j], ui);
            }
            float m2 = sqrtf(fmaf(ur, ur, ui * ui));
            const int q = s/2 - 24 + 2*t + r;
            if (edge) m2 = (q >= 0 && q < h1) ? m2 : 0.0f;
            mag[r] = m2;
            phv[r] = sh;
        }
        X2P[t] = packh2(mag[0], mag[1]);
        if (t >= 12) {                        // positions 24..511 owned
            long q0 = (long)s/2 - 24 + 2*t;
            *reinterpret_cast<float2*>(out + o1 + (long)b * h1 + q0) =
                make_float2(phv[0], phv[1]);
        }
    }
    // ---- Phase C tail: positions 512..559, 12 singles per wave ----
    if (lane < 12) {
        const int h   = 4 * lane + wv;        // 0..47
        const int pos = 512 + h;
        uint w8[8];
        #pragma unroll
        for (int j = 0; j < 8; ++j) w8[j] = X1P[pos + j];
        float sh = 0.f, ur = 0.f, ui = 0.f;
        #pragma unroll
        for (int j = 0; j < 8; ++j) {
            sh = dot2(FH[j], w8[j], sh);
            ur = dot2(FR[j], w8[j], ur);
            ui = dot2(FI[j], w8[j], ui);
        }
        float m2 = sqrtf(fmaf(ur, ur, ui * ui));
        const int q = s/2 - 24 + pos;
        if (edge) m2 = (q >= 0 && q < h1) ? m2 : 0.0f;
        reinterpret_cast<__fp16*>(X2P)[pos] = (__fp16)m2;
        if (h < 24)                            // positions 512..535 owned
            out[o1 + (long)b * h1 + q] = sh;
    }
    __syncthreads();

    // ---- Phase D: positions 0..271 (2/thread, 136 threads) ----
    if (tid < 136) {
        const int t = tid;
        uint2 u0 = *reinterpret_cast<const uint2*>(&X2P[2*t]);
        uint2 u1 = *reinterpret_cast<const uint2*>(&X2P[2*t+2]);
        uint2 u2 = *reinterpret_cast<const uint2*>(&X2P[2*t+4]);
        uint2 u3 = *reinterpret_cast<const uint2*>(&X2P[2*t+6]);
        uint  w8 = X2P[2*t+8];
        const uint w[9] = {u0.x,u0.y,u1.x,u1.y,u2.x,u2.y,u3.x,u3.y,w8};

        float phv[2], mag[2];
        #pragma unroll
        for (int r = 0; r < 2; ++r) {
            float sh = 0.f, ur = 0.f, ui = 0.f;
            #pragma unroll
            for (int j = 0; j < 8; ++j) {
                sh = dot2(FH[j], w[r+j], sh);
                ur = dot2(FR[j], w[r+j], ur);
                ui = dot2(FI[j], w[r+j], ui);
            }
            float m2 = sqrtf(fmaf(ur, ur, ui * ui));
            const int p = s/4 - 8 + 2*t + r;
            if (edge) m2 = (p >= 0 && p < h2) ? m2 : 0.0f;
            mag[r] = m2;
            phv[r] = sh;
        }
        X3P[t] = packh2(mag[0], mag[1]);
        if (t >= 4 && t < 132) {              // positions 8..263 owned
            long p0 = (long)s/4 - 8 + 2*t;
            *reinterpret_cast<float2*>(out + o2 + (long)b * h2 + p0) =
                make_float2(phv[0], phv[1]);
        }
    }
    __syncthreads();

    // ---- Phase E: level 3 -> c3 (phi only; x4 unused by reference) ----
    if (tid < S1/8) {
        float sh = 0.f;
        #pragma unroll
        for (int j = 0; j < 8; ++j)
            sh = dot2(FH[j], X3P[tid + j], sh);
        out[o3 + (long)b * h3 + (s/8 + tid)] = sh;
    }
}

extern "C" void kernel_launch(void* const* d_in, const int* in_sizes, int n_in,
                              void* d_out, int out_size, void* d_ws, size_t ws_size,
                              hipStream_t stream) {
    const float* xr    = (const float*)d_in[0];
    const float* xi    = (const float*)d_in[1];
    const float* psi_r = (const float*)d_in[2];
    const float* psi_i = (const float*)d_in[3];
    const float* phi   = (const float*)d_in[4];
    float* out = (float*)d_out;

    const int B  = 32;
    const int T  = in_sizes[0] / B;      // 524288
    const int L0 = T;
    const int h0 = L0 / 2;               // 262144
    const int h1 = h0 / 2;               // 131072
    const int h2 = h1 / 2;               // 65536
    const int h3 = h2 / 2;               // 32768

    const long o0 = 0;
    const long o1 = o0 + (long)B * h0;
    const long o2 = o1 + (long)B * h1;
    const long o3 = o2 + (long)B * h2;

    dim3 blk(NTH, 1, 1);
    dim3 grd(h0 / S1, B, 1);             // (256, 32)
    hipLaunchKernelGGL(hst_fused_kernel, grd, blk, 0, stream,
                       xr, xi, psi_r, psi_i, phi,
                       out, o0, o1, o2, o3,
                       L0, h0, h1, h2, h3);
}

// Round 13
// 47.370 us; speedup vs baseline: 1.1858x; 1.0412x over previous
//
#include <hip/hip_runtime.h>

// FastHST fused: 4-level 1-D scattering, B=32, T=524288, K=16, PAD=8.
// Output: real-contiguous f32 (confirmed r3; harness compares in bf16).
//
// r8 48.4us ref. r12: wave-balance helped (VALU 54%) but halo mapping
// h=4*lane+wv caused 16B-stride scalar LDS reads -> 2.16M bank-conflict
// cycles. r13: contiguous per-wave halo (h=28*wv+lane), S1=2048 (halo
// amortized 2x; all main passes exactly full: B=2x256 groups, C=256x4pos,
// D=256x2pos, E=256x1pos). MFMA ruled out: 3 useful filter cols of 32 ->
// epilogue concentrates in 6/64 lanes; wave-instr/pos worse than dot2.
//
// f16 packed-pair storage + v_dot2_f32_f16 (2 MAC/issue, f32 accum).

using f16x2 = __attribute__((ext_vector_type(2))) __fp16;

static __device__ __forceinline__ uint packh2(float a, float b) {
    f16x2 r = __builtin_amdgcn_cvt_pkrtz(a, b);
    return __builtin_bit_cast(uint, r);
}
static __device__ __forceinline__ float dot2(f16x2 f, uint w, float c) {
#if __has_builtin(__builtin_amdgcn_fdot2)
    return __builtin_amdgcn_fdot2(f, __builtin_bit_cast(f16x2, w), c, false);
#else
    f16x2 h = __builtin_bit_cast(f16x2, w);
    return fmaf((float)f.x, (float)h.x, fmaf((float)f.y, (float)h.y, c));
#endif
}

constexpr int S1   = 2048;
constexpr int H1   = 56;              // x1 halo each side
constexpr int NT1  = S1 + 2 * H1;     // 2160 x1 values/block
constexpr int NPIN = 2168;            // staged complex pairs (4336 floats)
constexpr int NLD  = NPIN / 2;        // 1084 float4 loads per stream
constexpr int NT2  = S1 / 2 + 48;     // 1072 (halo 24)
constexpr int NT3  = S1 / 4 + 16;     // 528 (halo 8)
constexpr int NTH  = 256;             // 4 waves

__global__ __launch_bounds__(NTH, 6) void hst_fused_kernel(
    const float* __restrict__ xr, const float* __restrict__ xi,
    const float* __restrict__ psi_r, const float* __restrict__ psi_i,
    const float* __restrict__ phi,
    float* __restrict__ out,
    long o0, long o1, long o2, long o3,
    int L0, int h0, int h1, int h2, int h3)
{
    __shared__ __align__(16) uint REP[NPIN];   // re f16 pairs, 8.7KB
    __shared__ __align__(16) uint IMP[NPIN];   // im pairs, 8.7KB
    __shared__ __align__(16) uint X1P[1080];   // x1: 2160 halfs, 4.3KB
    __shared__ __align__(16) uint X2P[536];    // x2: 1072 halfs, 2.1KB
    __shared__ __align__(16) uint X3P[264];    // x3: 528 halfs, 1.1KB

    const int tid  = threadIdx.x;
    const int wv   = tid >> 6;                // wave 0..3
    const int lane = tid & 63;
    const int gx   = blockIdx.x;
    const int b    = blockIdx.y;
    const int s    = gx * S1;                 // first owned x1 index
    const bool edge = (gx == 0) || (gx == (int)gridDim.x - 1);
    const int X0   = 2 * (s - H1) - 8;        // first staged input idx

    const float* rowr = xr + (size_t)b * (size_t)L0;
    const float* rowi = xi + (size_t)b * (size_t)L0;

    f16x2 FH[8], FR[8], FI[8];
    #pragma unroll
    for (int j = 0; j < 8; ++j) {
        FH[j] = __builtin_amdgcn_cvt_pkrtz(phi[2*j],   phi[2*j+1]);
        FR[j] = __builtin_amdgcn_cvt_pkrtz(psi_r[2*j], psi_r[2*j+1]);
        FI[j] = __builtin_amdgcn_cvt_pkrtz(psi_i[2*j], psi_i[2*j+1]);
    }

    // ---- Phase A: stage input as f16 pairs (tail contiguous 15/wave) ----
    if (!edge) {
        const float4* pr4 = reinterpret_cast<const float4*>(rowr + X0);
        const float4* pi4 = reinterpret_cast<const float4*>(rowi + X0);
        #pragma unroll
        for (int n = 0; n < 4; ++n) {
            const int i = tid + n * NTH;      // 0..1023, all full
            float4 a = pr4[i];
            float4 c = pi4[i];
            uint2 wa; wa.x = packh2(a.x, a.y); wa.y = packh2(a.z, a.w);
            uint2 wc; wc.x = packh2(c.x, c.y); wc.y = packh2(c.z, c.w);
            *reinterpret_cast<uint2*>(&REP[2*i]) = wa;
            *reinterpret_cast<uint2*>(&IMP[2*i]) = wc;
        }
        if (lane < 15) {
            const int i = 1024 + 15 * wv + lane;   // 1024..1083
            float4 a = pr4[i];
            float4 c = pi4[i];
            uint2 wa; wa.x = packh2(a.x, a.y); wa.y = packh2(a.z, a.w);
            uint2 wc; wc.x = packh2(c.x, c.y); wc.y = packh2(c.z, c.w);
            *reinterpret_cast<uint2*>(&REP[2*i]) = wa;
            *reinterpret_cast<uint2*>(&IMP[2*i]) = wc;
        }
    } else {
        for (int i = tid; i < NPIN; i += NTH) {
            int g0 = X0 + 2 * i;
            float r0 = (g0   >= 0 && g0   < L0) ? rowr[g0]   : 0.0f;
            float r1 = (g0+1 >= 0 && g0+1 < L0) ? rowr[g0+1] : 0.0f;
            float i0 = (g0   >= 0 && g0   < L0) ? rowi[g0]   : 0.0f;
            float i1 = (g0+1 >= 0 && g0+1 < L0) ? rowi[g0+1] : 0.0f;
            REP[i] = packh2(r0, r1);
            IMP[i] = packh2(i0, i1);
        }
    }
    __syncthreads();

    // ---- Phase B main: positions 0..2047, two full passes of 4/thread ----
    #pragma unroll
    for (int n = 0; n < 2; ++n) {
        const int g = tid + n * NTH;          // group: positions 4g..4g+3
        const uint4* wp = reinterpret_cast<const uint4*>(&REP[4*g]);
        uint4 a0 = wp[0], a1 = wp[1], a2 = wp[2];
        const uint4* ip = reinterpret_cast<const uint4*>(&IMP[4*g]);
        uint4 c0v = ip[0], c1v = ip[1], c2v = ip[2];
        const uint wr[12] = {a0.x,a0.y,a0.z,a0.w, a1.x,a1.y,a1.z,a1.w, a2.x,a2.y,a2.z,a2.w};
        const uint wi[12] = {c0v.x,c0v.y,c0v.z,c0v.w, c1v.x,c1v.y,c1v.z,c1v.w, c2v.x,c2v.y,c2v.z,c2v.w};

        float phv[4], mag[4];
        #pragma unroll
        for (int r = 0; r < 4; ++r) {
            float sh = 0.f, rr = 0.f, ri = 0.f, ir = 0.f, ii = 0.f;
            #pragma unroll
            for (int j = 0; j < 8; ++j) {
                sh = dot2(FH[j], wr[r+j], sh);
                rr = dot2(FR[j], wr[r+j], rr);
                ri = dot2(FI[j], wr[r+j], ri);
                ir = dot2(FR[j], wi[r+j], ir);
                ii = dot2(FI[j], wi[r+j], ii);
            }
            float ur = rr - ii, ui = ri + ir;
            float m2 = sqrtf(fmaf(ur, ur, ui * ui));
            if (edge) {
                int m = s - H1 + 4*g + r;
                m2 = (m >= 0 && m < h0) ? m2 : 0.0f;
            }
            mag[r] = m2;
            phv[r] = sh;
        }
        uint2 xp; xp.x = packh2(mag[0], mag[1]); xp.y = packh2(mag[2], mag[3]);
        *reinterpret_cast<uint2*>(&X1P[2*g]) = xp;

        if (g >= 14) {                        // positions 56.. owned
            long m0 = (long)s - H1 + 4*g;
            float4 st; st.x = phv[0]; st.y = phv[1]; st.z = phv[2]; st.w = phv[3];
            *reinterpret_cast<float4*>(out + o0 + (long)b * h0 + m0) = st;
        }
    }

    // ---- Phase B halo: positions 2048..2159, contiguous 28/wave ----
    if (lane < 28) {
        const int h  = 28 * wv + lane;        // 0..111
        const int lm = S1 + h;
        uint wr8[8], wi8[8];
        #pragma unroll
        for (int j = 0; j < 8; ++j) { wr8[j] = REP[lm + j]; wi8[j] = IMP[lm + j]; }
        float sh = 0.f, rr = 0.f, ri = 0.f, ir = 0.f, ii = 0.f;
        #pragma unroll
        for (int j = 0; j < 8; ++j) {
            sh = dot2(FH[j], wr8[j], sh);
            rr = dot2(FR[j], wr8[j], rr);
            ri = dot2(FI[j], wr8[j], ri);
            ir = dot2(FR[j], wi8[j], ir);
            ii = dot2(FI[j], wi8[j], ii);
        }
        float ur = rr - ii, ui = ri + ir;
        float m2 = sqrtf(fmaf(ur, ur, ui * ui));
        if (edge) {
            int m = s - H1 + lm;
            m2 = (m >= 0 && m < h0) ? m2 : 0.0f;
        }
        reinterpret_cast<__fp16*>(X1P)[lm] = (__fp16)m2;
        if (h < 56)                            // positions 2048..2103 owned
            out[o0 + (long)b * h0 + (s + S1 - H1 + h)] = sh;
    }
    __syncthreads();

    // ---- Phase C main: positions 0..1023, 4/thread (full) ----
    {
        const int t = tid;                    // positions 4t..4t+3, words 4t..4t+10
        const uint4* wp = reinterpret_cast<const uint4*>(&X1P[4*t]);
        uint4 a0 = wp[0], a1 = wp[1];
        uint2 u2 = *reinterpret_cast<const uint2*>(&X1P[4*t+8]);
        uint  w10 = X1P[4*t+10];
        const uint w[11] = {a0.x,a0.y,a0.z,a0.w, a1.x,a1.y,a1.z,a1.w, u2.x,u2.y, w10};

        float phv[4], mag[4];
        #pragma unroll
        for (int r = 0; r < 4; ++r) {
            float sh = 0.f, ur = 0.f, ui = 0.f;
            #pragma unroll
            for (int j = 0; j < 8; ++j) {
                sh = dot2(FH[j], w[r+j], sh);
                ur = dot2(FR[j], w[r+j], ur);
                ui = dot2(FI[j], w[r+j], ui);
            }
            float m2 = sqrtf(fmaf(ur, ur, ui * ui));
            const int q = s/2 - 24 + 4*t + r;
            if (edge) m2 = (q >= 0 && q < h1) ? m2 : 0.0f;
            mag[r] = m2;
            phv[r] = sh;
        }
        uint2 xp; xp.x = packh2(mag[0], mag[1]); xp.y = packh2(mag[2], mag[3]);
        *reinterpret_cast<uint2*>(&X2P[2*t]) = xp;

        if (t >= 6) {                         // positions 24..1023 owned
            long q0 = (long)s/2 - 24 + 4*t;
            float4 st; st.x = phv[0]; st.y = phv[1]; st.z = phv[2]; st.w = phv[3];
            *reinterpret_cast<float4*>(out + o1 + (long)b * h1 + q0) = st;
        }
    }
    // ---- Phase C tail: positions 1024..1071, contiguous 12/wave ----
    if (lane < 12) {
        const int h   = 12 * wv + lane;       // 0..47
        const int pos = 1024 + h;
        uint w8[8];
        #pragma unroll
        for (int j = 0; j < 8; ++j) w8[j] = X1P[pos + j];
        float sh = 0.f, ur = 0.f, ui = 0.f;
        #pragma unroll
        for (int j = 0; j < 8; ++j) {
            sh = dot2(FH[j], w8[j], sh);
            ur = dot2(FR[j], w8[j], ur);
            ui = dot2(FI[j], w8[j], ui);
        }
        float m2 = sqrtf(fmaf(ur, ur, ui * ui));
        const int q = s/2 - 24 + pos;
        if (edge) m2 = (q >= 0 && q < h1) ? m2 : 0.0f;
        reinterpret_cast<__fp16*>(X2P)[pos] = (__fp16)m2;
        if (h < 24)                            // positions 1024..1047 owned
            out[o1 + (long)b * h1 + q] = sh;
    }
    __syncthreads();

    // ---- Phase D main: positions 0..511, 2/thread (full) ----
    {
        const int t = tid;                    // positions 2t,2t+1, words 2t..2t+8
        uint2 u0 = *reinterpret_cast<const uint2*>(&X2P[2*t]);
        uint2 u1 = *reinterpret_cast<const uint2*>(&X2P[2*t+2]);
        uint2 u2 = *reinterpret_cast<const uint2*>(&X2P[2*t+4]);
        uint2 u3 = *reinterpret_cast<const uint2*>(&X2P[2*t+6]);
        uint  w8 = X2P[2*t+8];
        const uint w[9] = {u0.x,u0.y,u1.x,u1.y,u2.x,u2.y,u3.x,u3.y,w8};

        float phv[2], mag[2];
        #pragma unroll
        for (int r = 0; r < 2; ++r) {
            float sh = 0.f, ur = 0.f, ui = 0.f;
            #pragma unroll
            for (int j = 0; j < 8; ++j) {
                sh = dot2(FH[j], w[r+j], sh);
                ur = dot2(FR[j], w[r+j], ur);
                ui = dot2(FI[j], w[r+j], ui);
            }
            float m2 = sqrtf(fmaf(ur, ur, ui * ui));
            const int p = s/4 - 8 + 2*t + r;
            if (edge) m2 = (p >= 0 && p < h2) ? m2 : 0.0f;
            mag[r] = m2;
            phv[r] = sh;
        }
        X3P[t] = packh2(mag[0], mag[1]);
        if (t >= 4) {                         // positions 8..511 owned
            long p0 = (long)s/4 - 8 + 2*t;
            *reinterpret_cast<float2*>(out + o2 + (long)b * h2 + p0) =
                make_float2(phv[0], phv[1]);
        }
    }
    // ---- Phase D tail: positions 512..527, contiguous 4/wave ----
    if (lane < 4) {
        const int h   = 4 * wv + lane;        // 0..15
        const int pos = 512 + h;
        uint w8[8];
        #pragma unroll
        for (int j = 0; j < 8; ++j) w8[j] = X2P[pos + j];
        float sh = 0.f, ur = 0.f, ui = 0.f;
        #pragma unroll
        for (int j = 0; j < 8; ++j) {
            sh = dot2(FH[j], w8[j], sh);
            ur = dot2(FR[j], w8[j], ur);
            ui = dot2(FI[j], w8[j], ui);
        }
        float m2 = sqrtf(fmaf(ur, ur, ui * ui));
        const int p = s/4 - 8 + pos;
        if (edge) m2 = (p >= 0 && p < h2) ? m2 : 0.0f;
        reinterpret_cast<__fp16*>(X3P)[pos] = (__fp16)m2;
        if (h < 8)                             // positions 512..519 owned
            out[o2 + (long)b * h2 + p] = sh;
    }
    __syncthreads();

    // ---- Phase E: positions 0..255, 1/thread (full) ----
    {
        float sh = 0.f;
        #pragma unroll
        for (int j = 0; j < 8; ++j)
            sh = dot2(FH[j], X3P[tid + j], sh);
        out[o3 + (long)b * h3 + (s/8 + tid)] = sh;
    }
}

extern "C" void kernel_launch(void* const* d_in, const int* in_sizes, int n_in,
                              void* d_out, int out_size, void* d_ws, size_t ws_size,
                              hipStream_t stream) {
    const float* xr    = (const float*)d_in[0];
    const float* xi    = (const float*)d_in[1];
    const float* psi_r = (const float*)d_in[2];
    const float* psi_i = (const float*)d_in[3];
    const float* phi   = (const float*)d_in[4];
    float* out = (float*)d_out;

    const int B  = 32;
    const int T  = in_sizes[0] / B;      // 524288
    const int L0 = T;
    const int h0 = L0 / 2;               // 262144
    const int h1 = h0 / 2;               // 131072
    const int h2 = h1 / 2;               // 65536
    const int h3 = h2 / 2;               // 32768

    const long o0 = 0;
    const long o1 = o0 + (long)B * h0;
    const long o2 = o1 + (long)B * h1;
    const long o3 = o2 + (long)B * h2;

    dim3 blk(NTH, 1, 1);
    dim3 grd(h0 / S1, B, 1);             // (128, 32)
    hipLaunchKernelGGL(hst_fused_kernel, grd, blk, 0, stream,
                       xr, xi, psi_r, psi_i, phi,
                       out, o0, o1, o2, o3,
                       L0, h0, h1, h2, h3);
}

// Round 14
// 46.042 us; speedup vs baseline: 1.2200x; 1.0288x over previous
//
#include <hip/hip_runtime.h>

// FastHST fused: 4-level 1-D scattering, B=32, T=524288, K=16, PAD=8.
// Output: real-contiguous f32 (confirmed r3; harness compares in bf16).
//
// r13 47.4us ref (balanced tiling, contiguous halo maps, conflicts 32K).
// r14: Karatsuba in-register for level 0 (r10's fail was the 3rd LDS stream
// + 64-VGPR cap; here ws=wr+wi via 12 v_pk_add_f16/thread, cap stays 85):
//   A=conv(psi_r,re), B=conv(psi_i,im), C=conv(psi_r+psi_i, re+im)
//   ur=A-B, ui=C-A-B. Phase B: 40 -> 32 dot2/position.
//
// f16 packed-pair storage + v_dot2_f32_f16 (2 MAC/issue, f32 accum).

using f16x2 = __attribute__((ext_vector_type(2))) __fp16;

static __device__ __forceinline__ uint packh2(float a, float b) {
    f16x2 r = __builtin_amdgcn_cvt_pkrtz(a, b);
    return __builtin_bit_cast(uint, r);
}
static __device__ __forceinline__ uint pkadd(uint a, uint b) {
    f16x2 x = __builtin_bit_cast(f16x2, a);
    f16x2 y = __builtin_bit_cast(f16x2, b);
    f16x2 r = x + y;                           // v_pk_add_f16
    return __builtin_bit_cast(uint, r);
}
static __device__ __forceinline__ float dot2(f16x2 f, uint w, float c) {
#if __has_builtin(__builtin_amdgcn_fdot2)
    return __builtin_amdgcn_fdot2(f, __builtin_bit_cast(f16x2, w), c, false);
#else
    f16x2 h = __builtin_bit_cast(f16x2, w);
    return fmaf((float)f.x, (float)h.x, fmaf((float)f.y, (float)h.y, c));
#endif
}

constexpr int S1   = 2048;
constexpr int H1   = 56;              // x1 halo each side
constexpr int NT1  = S1 + 2 * H1;     // 2160 x1 values/block
constexpr int NPIN = 2168;            // staged complex pairs (4336 floats)
constexpr int NTH  = 256;             // 4 waves

__global__ __launch_bounds__(NTH, 6) void hst_fused_kernel(
    const float* __restrict__ xr, const float* __restrict__ xi,
    const float* __restrict__ psi_r, const float* __restrict__ psi_i,
    const float* __restrict__ phi,
    float* __restrict__ out,
    long o0, long o1, long o2, long o3,
    int L0, int h0, int h1, int h2, int h3)
{
    __shared__ __align__(16) uint REP[NPIN];   // re f16 pairs, 8.7KB
    __shared__ __align__(16) uint IMP[NPIN];   // im pairs, 8.7KB
    __shared__ __align__(16) uint X1P[1080];   // x1: 2160 halfs, 4.3KB
    __shared__ __align__(16) uint X2P[536];    // x2: 1072 halfs, 2.1KB
    __shared__ __align__(16) uint X3P[264];    // x3: 528 halfs, 1.1KB

    const int tid  = threadIdx.x;
    const int wv   = tid >> 6;                // wave 0..3
    const int lane = tid & 63;
    const int gx   = blockIdx.x;
    const int b    = blockIdx.y;
    const int s    = gx * S1;                 // first owned x1 index
    const bool edge = (gx == 0) || (gx == (int)gridDim.x - 1);
    const int X0   = 2 * (s - H1) - 8;        // first staged input idx

    const float* rowr = xr + (size_t)b * (size_t)L0;
    const float* rowi = xi + (size_t)b * (size_t)L0;

    f16x2 FH[8], FR[8], FI[8], FS[8];
    #pragma unroll
    for (int j = 0; j < 8; ++j) {
        FH[j] = __builtin_amdgcn_cvt_pkrtz(phi[2*j],   phi[2*j+1]);
        FR[j] = __builtin_amdgcn_cvt_pkrtz(psi_r[2*j], psi_r[2*j+1]);
        FI[j] = __builtin_amdgcn_cvt_pkrtz(psi_i[2*j], psi_i[2*j+1]);
        FS[j] = __builtin_amdgcn_cvt_pkrtz(psi_r[2*j] + psi_i[2*j],
                                           psi_r[2*j+1] + psi_i[2*j+1]);
    }

    // ---- Phase A: stage input as f16 pairs (tail contiguous 15/wave) ----
    if (!edge) {
        const float4* pr4 = reinterpret_cast<const float4*>(rowr + X0);
        const float4* pi4 = reinterpret_cast<const float4*>(rowi + X0);
        #pragma unroll
        for (int n = 0; n < 4; ++n) {
            const int i = tid + n * NTH;      // 0..1023, all full
            float4 a = pr4[i];
            float4 c = pi4[i];
            uint2 wa; wa.x = packh2(a.x, a.y); wa.y = packh2(a.z, a.w);
            uint2 wc; wc.x = packh2(c.x, c.y); wc.y = packh2(c.z, c.w);
            *reinterpret_cast<uint2*>(&REP[2*i]) = wa;
            *reinterpret_cast<uint2*>(&IMP[2*i]) = wc;
        }
        if (lane < 15) {
            const int i = 1024 + 15 * wv + lane;   // 1024..1083
            float4 a = pr4[i];
            float4 c = pi4[i];
            uint2 wa; wa.x = packh2(a.x, a.y); wa.y = packh2(a.z, a.w);
            uint2 wc; wc.x = packh2(c.x, c.y); wc.y = packh2(c.z, c.w);
            *reinterpret_cast<uint2*>(&REP[2*i]) = wa;
            *reinterpret_cast<uint2*>(&IMP[2*i]) = wc;
        }
    } else {
        for (int i = tid; i < NPIN; i += NTH) {
            int g0 = X0 + 2 * i;
            float r0 = (g0   >= 0 && g0   < L0) ? rowr[g0]   : 0.0f;
            float r1 = (g0+1 >= 0 && g0+1 < L0) ? rowr[g0+1] : 0.0f;
            float i0 = (g0   >= 0 && g0   < L0) ? rowi[g0]   : 0.0f;
            float i1 = (g0+1 >= 0 && g0+1 < L0) ? rowi[g0+1] : 0.0f;
            REP[i] = packh2(r0, r1);
            IMP[i] = packh2(i0, i1);
        }
    }
    __syncthreads();

    // ---- Phase B main: positions 0..2047, two full passes of 4/thread ----
    #pragma unroll
    for (int n = 0; n < 2; ++n) {
        const int g = tid + n * NTH;          // group: positions 4g..4g+3
        const uint4* wp = reinterpret_cast<const uint4*>(&REP[4*g]);
        uint4 a0 = wp[0], a1 = wp[1], a2 = wp[2];
        const uint4* ip = reinterpret_cast<const uint4*>(&IMP[4*g]);
        uint4 c0v = ip[0], c1v = ip[1], c2v = ip[2];
        const uint wr[12] = {a0.x,a0.y,a0.z,a0.w, a1.x,a1.y,a1.z,a1.w, a2.x,a2.y,a2.z,a2.w};
        const uint wi[12] = {c0v.x,c0v.y,c0v.z,c0v.w, c1v.x,c1v.y,c1v.z,c1v.w, c2v.x,c2v.y,c2v.z,c2v.w};
        uint ws[12];
        #pragma unroll
        for (int j = 0; j < 12; ++j) ws[j] = pkadd(wr[j], wi[j]);

        float phv[4], mag[4];
        #pragma unroll
        for (int r = 0; r < 4; ++r) {
            float sh = 0.f, A = 0.f, Bv = 0.f, C = 0.f;
            #pragma unroll
            for (int j = 0; j < 8; ++j) {
                sh = dot2(FH[j], wr[r+j], sh);
                A  = dot2(FR[j], wr[r+j], A);
                Bv = dot2(FI[j], wi[r+j], Bv);
                C  = dot2(FS[j], ws[r+j], C);
            }
            float ur = A - Bv;
            float ui = C - (A + Bv);
            float m2 = sqrtf(fmaf(ur, ur, ui * ui));
            if (edge) {
                int m = s - H1 + 4*g + r;
                m2 = (m >= 0 && m < h0) ? m2 : 0.0f;
            }
            mag[r] = m2;
            phv[r] = sh;
        }
        uint2 xp; xp.x = packh2(mag[0], mag[1]); xp.y = packh2(mag[2], mag[3]);
        *reinterpret_cast<uint2*>(&X1P[2*g]) = xp;

        if (g >= 14) {                        // positions 56.. owned
            long m0 = (long)s - H1 + 4*g;
            float4 st; st.x = phv[0]; st.y = phv[1]; st.z = phv[2]; st.w = phv[3];
            *reinterpret_cast<float4*>(out + o0 + (long)b * h0 + m0) = st;
        }
    }

    // ---- Phase B halo: positions 2048..2159, contiguous 28/wave ----
    if (lane < 28) {
        const int h  = 28 * wv + lane;        // 0..111
        const int lm = S1 + h;
        uint wr8[8], wi8[8], ws8[8];
        #pragma unroll
        for (int j = 0; j < 8; ++j) {
            wr8[j] = REP[lm + j]; wi8[j] = IMP[lm + j];
            ws8[j] = pkadd(wr8[j], wi8[j]);
        }
        float sh = 0.f, A = 0.f, Bv = 0.f, C = 0.f;
        #pragma unroll
        for (int j = 0; j < 8; ++j) {
            sh = dot2(FH[j], wr8[j], sh);
            A  = dot2(FR[j], wr8[j], A);
            Bv = dot2(FI[j], wi8[j], Bv);
            C  = dot2(FS[j], ws8[j], C);
        }
        float ur = A - Bv;
        float ui = C - (A + Bv);
        float m2 = sqrtf(fmaf(ur, ur, ui * ui));
        if (edge) {
            int m = s - H1 + lm;
            m2 = (m >= 0 && m < h0) ? m2 : 0.0f;
        }
        reinterpret_cast<__fp16*>(X1P)[lm] = (__fp16)m2;
        if (h < 56)                            // positions 2048..2103 owned
            out[o0 + (long)b * h0 + (s + S1 - H1 + h)] = sh;
    }
    __syncthreads();

    // ---- Phase C main: positions 0..1023, 4/thread (full) ----
    {
        const int t = tid;                    // positions 4t..4t+3, words 4t..4t+10
        const uint4* wp = reinterpret_cast<const uint4*>(&X1P[4*t]);
        uint4 a0 = wp[0], a1 = wp[1];
        uint2 u2 = *reinterpret_cast<const uint2*>(&X1P[4*t+8]);
        uint  w10 = X1P[4*t+10];
        const uint w[11] = {a0.x,a0.y,a0.z,a0.w, a1.x,a1.y,a1.z,a1.w, u2.x,u2.y, w10};

        float phv[4], mag[4];
        #pragma unroll
        for (int r = 0; r < 4; ++r) {
            float sh = 0.f, ur = 0.f, ui = 0.f;
            #pragma unroll
            for (int j = 0; j < 8; ++j) {
                sh = dot2(FH[j], w[r+j], sh);
                ur = dot2(FR[j], w[r+j], ur);
                ui = dot2(FI[j], w[r+j], ui);
            }
            float m2 = sqrtf(fmaf(ur, ur, ui * ui));
            const int q = s/2 - 24 + 4*t + r;
            if (edge) m2 = (q >= 0 && q < h1) ? m2 : 0.0f;
            mag[r] = m2;
            phv[r] = sh;
        }
        uint2 xp; xp.x = packh2(mag[0], mag[1]); xp.y = packh2(mag[2], mag[3]);
        *reinterpret_cast<uint2*>(&X2P[2*t]) = xp;

        if (t >= 6) {                         // positions 24..1023 owned
            long q0 = (long)s/2 - 24 + 4*t;
            float4 st; st.x = phv[0]; st.y = phv[1]; st.z = phv[2]; st.w = phv[3];
            *reinterpret_cast<float4*>(out + o1 + (long)b * h1 + q0) = st;
        }
    }
    // ---- Phase C tail: positions 1024..1071, contiguous 12/wave ----
    if (lane < 12) {
        const int h   = 12 * wv + lane;       // 0..47
        const int pos = 1024 + h;
        uint w8[8];
        #pragma unroll
        for (int j = 0; j < 8; ++j) w8[j] = X1P[pos + j];
        float sh = 0.f, ur = 0.f, ui = 0.f;
        #pragma unroll
        for (int j = 0; j < 8; ++j) {
            sh = dot2(FH[j], w8[j], sh);
            ur = dot2(FR[j], w8[j], ur);
            ui = dot2(FI[j], w8[j], ui);
        }
        float m2 = sqrtf(fmaf(ur, ur, ui * ui));
        const int q = s/2 - 24 + pos;
        if (edge) m2 = (q >= 0 && q < h1) ? m2 : 0.0f;
        reinterpret_cast<__fp16*>(X2P)[pos] = (__fp16)m2;
        if (h < 24)                            // positions 1024..1047 owned
            out[o1 + (long)b * h1 + q] = sh;
    }
    __syncthreads();

    // ---- Phase D main: positions 0..511, 2/thread (full) ----
    {
        const int t = tid;                    // positions 2t,2t+1, words 2t..2t+8
        uint2 u0 = *reinterpret_cast<const uint2*>(&X2P[2*t]);
        uint2 u1 = *reinterpret_cast<const uint2*>(&X2P[2*t+2]);
        uint2 u2 = *reinterpret_cast<const uint2*>(&X2P[2*t+4]);
        uint2 u3 = *reinterpret_cast<const uint2*>(&X2P[2*t+6]);
        uint  w8 = X2P[2*t+8];
        const uint w[9] = {u0.x,u0.y,u1.x,u1.y,u2.x,u2.y,u3.x,u3.y,w8};

        float phv[2], mag[2];
        #pragma unroll
        for (int r = 0; r < 2; ++r) {
            float sh = 0.f, ur = 0.f, ui = 0.f;
            #pragma unroll
            for (int j = 0; j < 8; ++j) {
                sh = dot2(FH[j], w[r+j], sh);
                ur = dot2(FR[j], w[r+j], ur);
                ui = dot2(FI[j], w[r+j], ui);
            }
            float m2 = sqrtf(fmaf(ur, ur, ui * ui));
            const int p = s/4 - 8 + 2*t + r;
            if (edge) m2 = (p >= 0 && p < h2) ? m2 : 0.0f;
            mag[r] = m2;
            phv[r] = sh;
        }
        X3P[t] = packh2(mag[0], mag[1]);
        if (t >= 4) {                         // positions 8..511 owned
            long p0 = (long)s/4 - 8 + 2*t;
            *reinterpret_cast<float2*>(out + o2 + (long)b * h2 + p0) =
                make_float2(phv[0], phv[1]);
        }
    }
    // ---- Phase D tail: positions 512..527, contiguous 4/wave ----
    if (lane < 4) {
        const int h   = 4 * wv + lane;        // 0..15
        const int pos = 512 + h;
        uint w8[8];
        #pragma unroll
        for (int j = 0; j < 8; ++j) w8[j] = X2P[pos + j];
        float sh = 0.f, ur = 0.f, ui = 0.f;
        #pragma unroll
        for (int j = 0; j < 8; ++j) {
            sh = dot2(FH[j], w8[j], sh);
            ur = dot2(FR[j], w8[j], ur);
            ui = dot2(FI[j], w8[j], ui);
        }
        float m2 = sqrtf(fmaf(ur, ur, ui * ui));
        const int p = s/4 - 8 + pos;
        if (edge) m2 = (p >= 0 && p < h2) ? m2 : 0.0f;
        reinterpret_cast<__fp16*>(X3P)[pos] = (__fp16)m2;
        if (h < 8)                             // positions 512..519 owned
            out[o2 + (long)b * h2 + p] = sh;
    }
    __syncthreads();

    // ---- Phase E: positions 0..255, 1/thread (full) ----
    {
        float sh = 0.f;
        #pragma unroll
        for (int j = 0; j < 8; ++j)
            sh = dot2(FH[j], X3P[tid + j], sh);
        out[o3 + (long)b * h3 + (s/8 + tid)] = sh;
    }
}

extern "C" void kernel_launch(void* const* d_in, const int* in_sizes, int n_in,
                              void* d_out, int out_size, void* d_ws, size_t ws_size,
                              hipStream_t stream) {
    const float* xr    = (const float*)d_in[0];
    const float* xi    = (const float*)d_in[1];
    const float* psi_r = (const float*)d_in[2];
    const float* psi_i = (const float*)d_in[3];
    const float* phi   = (const float*)d_in[4];
    float* out = (float*)d_out;

    const int B  = 32;
    const int T  = in_sizes[0] / B;      // 524288
    const int L0 = T;
    const int h0 = L0 / 2;               // 262144
    const int h1 = h0 / 2;               // 131072
    const int h2 = h1 / 2;               // 65536
    const int h3 = h2 / 2;               // 32768

    const long o0 = 0;
    const long o1 = o0 + (long)B * h0;
    const long o2 = o1 + (long)B * h1;
    const long o3 = o2 + (long)B * h2;

    dim3 blk(NTH, 1, 1);
    dim3 grd(h0 / S1, B, 1);             // (128, 32)
    hipLaunchKernelGGL(hst_fused_kernel, grd, blk, 0, stream,
                       xr, xi, psi_r, psi_i, phi,
                       out, o0, o1, o2, o3,
                       L0, h0, h1, h2, h3);
}